// Round 13
// baseline (438.517 us; speedup 1.0000x reference)
//
#include <hip/hip_runtime.h>
#include <hip/hip_cooperative_groups.h>
#include <hip/hip_bf16.h>

namespace cg = cooperative_groups;

#define Bb 2
#define HD 96
#define DI 192
#define LL 4096
#define Kd 4
#define Ns 16
#define Rr 6
#define SEG 256
#define SEGLEN 16
#define NTASK (SEG*Kd*Bb)     // 2048
#define NBKCN (Bb*Kd*DI*Ns)   // 24576
#define LNEPS 1e-5f
#define RW 40                  // dblp row: 6 dt | 2 pad | 16 B | 16 C
#define LOG2E 1.44269504f

// fused: in_conv(96->96) + chanLN + in_proj(96->192)
__global__ __launch_bounds__(384) void k_fused_in(const float* __restrict__ x,
    const float* __restrict__ w1, const float* __restrict__ g, const float* __restrict__ be,
    const float* __restrict__ w2, float* __restrict__ x1, float* __restrict__ hp) {
  __shared__ float xs[16][100];
  __shared__ float t1[16][100];
  __shared__ float red[2][16][24];
  int t = threadIdx.x;
  int l0 = blockIdx.x*16; int b = blockIdx.y;
  for (int idx=t; idx<HD*16; idx+=384) {
    int c = idx>>4, i = idx&15;
    xs[i][c] = x[((size_t)b*HD + c)*LL + l0 + i];
  }
  __syncthreads();
  int l = t & 15, cg0 = t >> 4;
  float a0=0.f,a1=0.f,a2=0.f,a3=0.f;
  {
    const float4* xr = (const float4*)&xs[l][0];
    const float4* wr0 = (const float4*)(w1 + (size_t)(cg0*4+0)*HD);
    const float4* wr1 = (const float4*)(w1 + (size_t)(cg0*4+1)*HD);
    const float4* wr2 = (const float4*)(w1 + (size_t)(cg0*4+2)*HD);
    const float4* wr3 = (const float4*)(w1 + (size_t)(cg0*4+3)*HD);
    #pragma unroll 6
    for (int j=0;j<24;j++) {
      float4 xv = xr[j];
      float4 v0 = wr0[j], v1 = wr1[j], v2 = wr2[j], v3 = wr3[j];
      a0 += xv.x*v0.x + xv.y*v0.y + xv.z*v0.z + xv.w*v0.w;
      a1 += xv.x*v1.x + xv.y*v1.y + xv.z*v1.z + xv.w*v1.w;
      a2 += xv.x*v2.x + xv.y*v2.y + xv.z*v2.z + xv.w*v2.w;
      a3 += xv.x*v3.x + xv.y*v3.y + xv.z*v3.z + xv.w*v3.w;
    }
  }
  float s = a0+a1+a2+a3;
  float s2 = a0*a0+a1*a1+a2*a2+a3*a3;
  red[0][l][cg0]=s; red[1][l][cg0]=s2;
  __syncthreads();
  float S=0.f, S2=0.f;
  #pragma unroll
  for (int q=0;q<24;q++) { S += red[0][l][q]; S2 += red[1][l][q]; }
  float mu = S*(1.f/HD);
  float var = S2*(1.f/HD) - mu*mu;
  float r = rsqrtf(var + LNEPS);
  {
    int c0 = cg0*4;
    float v0 = (a0-mu)*r*g[c0+0] + be[c0+0];
    float v1 = (a1-mu)*r*g[c0+1] + be[c0+1];
    float v2 = (a2-mu)*r*g[c0+2] + be[c0+2];
    float v3 = (a3-mu)*r*g[c0+3] + be[c0+3];
    t1[l][c0+0]=v0; t1[l][c0+1]=v1; t1[l][c0+2]=v2; t1[l][c0+3]=v3;
    size_t ob = ((size_t)b*HD + c0)*LL + l0 + l;
    x1[ob]=v0; x1[ob+LL]=v1; x1[ob+2*(size_t)LL]=v2; x1[ob+3*(size_t)LL]=v3;
  }
  __syncthreads();
  float acc[8];
  #pragma unroll
  for (int q=0;q<8;q++) acc[q]=0.f;
  {
    const float4* yr = (const float4*)&t1[l][0];
    #pragma unroll 4
    for (int j=0;j<24;j++) {
      float4 yv = yr[j];
      #pragma unroll
      for (int q=0;q<8;q++) {
        float4 wv = ((const float4*)(w2 + (size_t)(cg0*8+q)*HD))[j];
        acc[q] += yv.x*wv.x + yv.y*wv.y + yv.z*wv.z + yv.w*wv.w;
      }
    }
  }
  #pragma unroll
  for (int q=0;q<8;q++)
    hp[((size_t)b*DI + cg0*8+q)*LL + l0 + l] = acc[q];
}

// depthwise 3x3 + bias + silu -> channel-last v_t[b][p][c]; 24-ch slabs
__global__ __launch_bounds__(192) void k_dwconv_silu_t(const float* __restrict__ hp,
    const float* __restrict__ wgt, const float* __restrict__ bias, float* __restrict__ v_t) {
  __shared__ float lds[24*65];
  int t = threadIdx.x;
  int w0 = t & 63, dg = t >> 6;
  int h = blockIdx.x, dq = blockIdx.y, b = blockIdx.z;
  for (int dd=0; dd<8; ++dd) {
    int dl = dg*8 + dd;
    int d = dq*24 + dl;
    const float* src = hp + ((size_t)b*DI + d)*LL;
    const float* wk = wgt + d*9;
    float acc = bias[d];
    #pragma unroll
    for (int dy=-1; dy<=1; dy++) {
      int hh = h+dy;
      if (hh < 0 || hh >= 64) continue;
      #pragma unroll
      for (int dx=-1; dx<=1; dx++) {
        int ww = w0+dx;
        if (ww < 0 || ww >= 64) continue;
        acc += wk[(dy+1)*3 + (dx+1)] * src[hh*64 + ww];
      }
    }
    lds[dl*65 + w0] = acc / (1.f + __expf(-acc));
  }
  __syncthreads();
  int hc = t % 24, ig = t / 24;
  if (ig < 8) {
    for (int ii=0; ii<8; ii++) {
      int i = ig*8 + ii;
      v_t[((size_t)b*LL + h*64 + i)*DI + dq*24 + hc] = lds[hc*65 + i];
    }
  }
}

// dblp[b][k][p][40] = W_k(38x192).v_row(p); 512 thr = (p=t&63, dg=t>>6 wave-uniform)
__global__ __launch_bounds__(512) void k_proj(const float* __restrict__ v_t,
    const float* __restrict__ xpw, float* __restrict__ dblp) {
  __shared__ float lds[64*196];
  int t = threadIdx.x;
  int pt = blockIdx.x, k = blockIdx.y, b = blockIdx.z;
  const float4* src = (const float4*)(v_t + ((size_t)b*LL + pt*64)*DI);
  for (int idx=t; idx<64*48; idx+=512) {
    int p = idx/48, q = idx - p*48;
    *((float4*)&lds[p*196 + 4*q]) = src[idx];
  }
  __syncthreads();
  int p = t & 63, dg = t >> 6;
  int d0 = (dg<6) ? dg*5 : 30 + (dg-6)*4;
  int nd = (dg<6) ? 5 : 4;
  float acc[5];
  #pragma unroll
  for (int q=0;q<5;q++) acc[q]=0.f;
  const float4* W4 = (const float4*)(xpw + (size_t)(k*38 + d0)*DI);
  const float4* row4 = (const float4*)(lds + p*196);
  for (int c4=0;c4<48;c4++) {
    float4 xv = row4[c4];
    #pragma unroll
    for (int dd=0;dd<5;dd++) {
      if (dd < nd) {
        float4 wv = W4[(size_t)dd*48 + c4];
        acc[dd] += xv.x*wv.x + xv.y*wv.y + xv.z*wv.z + xv.w*wv.w;
      }
    }
  }
  float* o = dblp + (((size_t)b*4 + k)*LL + pt*64 + p)*RW;
  for (int dd=0;dd<nd;dd++) {
    int d = d0 + dd;
    o[d + ((d>=6)?2:0)] = acc[dd];
  }
}

__device__ __forceinline__ void dir_map(int k, int s, int& pbase, int& pstr) {
  if (k==0)      { pbase = s*16;                          pstr = 1;   }
  else if (k==1) { pbase = (s&3)*1024 + (s>>2);           pstr = 64;  }
  else if (k==2) { pbase = 4095 - s*16;                   pstr = -1;  }
  else           { pbase = 4095 - (s&3)*1024 - (s>>2);    pstr = -64; }
}

__device__ __forceinline__ float softplus_f(float raw) {
  float e = __expf(raw);
  float l = __logf(1.f + e);
  return (raw > 20.f) ? raw : l;
}

// cooperative: scanA -> grid.sync -> fix -> grid.sync -> scanB  (one launch)
__global__ __launch_bounds__(192, 3) void k_scan_all(
    const float* __restrict__ v_t, const float* __restrict__ dblp,
    const float* __restrict__ dtw, const float* __restrict__ dtb,
    const float* __restrict__ A_log, float* __restrict__ hend,
    float* __restrict__ sdt_o, float* __restrict__ ym) {
  cg::grid_group grid = cg::this_grid();
  __shared__ float uld[SEGLEN][DI];
  __shared__ float rows[SEGLEN][RW];
  int t = threadIdx.x;
  int c = t;

  // ---------- phase A: per-segment zero-init scan ----------
  for (int task = blockIdx.x; task < NTASK; task += gridDim.x) {
    int s = task & (SEG-1);
    int k = (task >> 8) & 3;
    int b = task >> 10;
    int bk = b*4 + k;
    int pbase, pstr; dir_map(k, s, pbase, pstr);
    __syncthreads();   // LDS reuse across tasks
    #pragma unroll
    for (int i=0;i<4;i++) {
      int idx = t + i*192;
      int row = idx/48, q = idx - row*48;
      int p = pbase + row*pstr;
      *((float4*)&uld[row][4*q]) = ((const float4*)(v_t + ((size_t)b*LL + p)*DI))[q];
    }
    if (t < 96) {
      int r = t/6, q = t - r*6;
      *((float4*)&rows[r][4*q]) = ((const float4*)(dblp + ((size_t)bk*LL + pbase + r*pstr)*RW))[q];
    }
    float w[6];
    {
      const float* wr = dtw + ((size_t)k*DI + c)*Rr;
      #pragma unroll
      for (int r=0;r<6;r++) w[r] = wr[r];
    }
    float bias = dtb[k*DI + c];
    float A2[16];
    {
      const float4* Ap = (const float4*)(A_log + ((size_t)k*DI + c)*Ns);
      #pragma unroll
      for (int q=0;q<4;q++) {
        float4 av = Ap[q];
        A2[4*q+0]=-__expf(av.x)*LOG2E; A2[4*q+1]=-__expf(av.y)*LOG2E;
        A2[4*q+2]=-__expf(av.z)*LOG2E; A2[4*q+3]=-__expf(av.w)*LOG2E;
      }
    }
    __syncthreads();
    float dtv[SEGLEN], duv[SEGLEN];
    float sdt = 0.f;
    #pragma unroll
    for (int j=0;j<SEGLEN;j++) {
      const float* row = &rows[j][0];
      float4 d0 = *((const float4*)row);
      float2 d1 = *((const float2*)(row+4));
      float raw = bias + w[0]*d0.x + w[1]*d0.y + w[2]*d0.z + w[3]*d0.w
                + w[4]*d1.x + w[5]*d1.y;
      float dt = softplus_f(raw);
      dtv[j] = dt;
      duv[j] = dt * uld[j][c];
      sdt += dt;
    }
    float h[16];
    #pragma unroll
    for (int n=0;n<16;n++) h[n]=0.f;
    #pragma unroll
    for (int j=0;j<SEGLEN;j++) {
      float dt = dtv[j], du = duv[j];
      const float4* Bv = (const float4*)(&rows[j][8]);
      #pragma unroll
      for (int q=0;q<4;q++) {
        float4 bv = Bv[q];
        h[4*q+0] = h[4*q+0]*__builtin_amdgcn_exp2f(dt*A2[4*q+0]) + du*bv.x;
        h[4*q+1] = h[4*q+1]*__builtin_amdgcn_exp2f(dt*A2[4*q+1]) + du*bv.y;
        h[4*q+2] = h[4*q+2]*__builtin_amdgcn_exp2f(dt*A2[4*q+2]) + du*bv.z;
        h[4*q+3] = h[4*q+3]*__builtin_amdgcn_exp2f(dt*A2[4*q+3]) + du*bv.w;
      }
    }
    float* ho = hend + ((size_t)s*8 + bk)*(DI*Ns) + c;
    #pragma unroll
    for (int n=0;n<16;n++) ho[(size_t)n*DI] = h[n];
    sdt_o[((size_t)s*8 + bk)*DI + c] = sdt;
  }
  grid.sync();
  // ---------- fix: hend -> h_init in place ----------
  for (int gix = blockIdx.x*192 + t; gix < NBKCN; gix += gridDim.x*192) {
    int cc = gix % DI;
    int nn = (gix / DI) & 15;
    int bk = gix / (DI*Ns);
    int k = bk & 3;
    float A = -__expf(A_log[((size_t)k*DI + cc)*Ns + nn]);
    float hi = 0.f;
    #pragma unroll 8
    for (int s=0; s<SEG; s++) {
      float he = hend[(size_t)s*NBKCN + gix];
      float P  = __expf(A * sdt_o[(size_t)s*(8*DI) + bk*DI + cc]);
      hend[(size_t)s*NBKCN + gix] = hi;
      hi = he + P*hi;
    }
  }
  grid.sync();
  // ---------- phase B: rescan from h_init, emit y ----------
  for (int task = blockIdx.x; task < NTASK; task += gridDim.x) {
    int s = task & (SEG-1);
    int k = (task >> 8) & 3;
    int b = task >> 10;
    int bk = b*4 + k;
    int pbase, pstr; dir_map(k, s, pbase, pstr);
    __syncthreads();
    #pragma unroll
    for (int i=0;i<4;i++) {
      int idx = t + i*192;
      int row = idx/48, q = idx - row*48;
      int p = pbase + row*pstr;
      *((float4*)&uld[row][4*q]) = ((const float4*)(v_t + ((size_t)b*LL + p)*DI))[q];
    }
    if (t < 160) {
      int r = t/10, q = t - r*10;
      *((float4*)&rows[r][4*q]) = ((const float4*)(dblp + ((size_t)bk*LL + pbase + r*pstr)*RW))[q];
    }
    float w[6];
    {
      const float* wr = dtw + ((size_t)k*DI + c)*Rr;
      #pragma unroll
      for (int r=0;r<6;r++) w[r] = wr[r];
    }
    float bias = dtb[k*DI + c];
    float A2[16];
    {
      const float4* Ap = (const float4*)(A_log + ((size_t)k*DI + c)*Ns);
      #pragma unroll
      for (int q=0;q<4;q++) {
        float4 av = Ap[q];
        A2[4*q+0]=-__expf(av.x)*LOG2E; A2[4*q+1]=-__expf(av.y)*LOG2E;
        A2[4*q+2]=-__expf(av.z)*LOG2E; A2[4*q+3]=-__expf(av.w)*LOG2E;
      }
    }
    float h[16];
    {
      const float* hi = hend + ((size_t)s*8 + bk)*(DI*Ns) + c;
      #pragma unroll
      for (int n=0;n<16;n++) h[n] = hi[(size_t)n*DI];
    }
    __syncthreads();
    float dtv[SEGLEN], duv[SEGLEN];
    #pragma unroll
    for (int j=0;j<SEGLEN;j++) {
      const float* row = &rows[j][0];
      float4 d0 = *((const float4*)row);
      float2 d1 = *((const float2*)(row+4));
      float raw = bias + w[0]*d0.x + w[1]*d0.y + w[2]*d0.z + w[3]*d0.w
                + w[4]*d1.x + w[5]*d1.y;
      float dt = softplus_f(raw);
      dtv[j] = dt;
      duv[j] = dt * uld[j][c];
    }
    float* ymk = ym + ((size_t)(k*Bb + b)*LL)*DI;
    #pragma unroll
    for (int j=0;j<SEGLEN;j++) {
      float dt = dtv[j], du = duv[j];
      const float4* Bv = (const float4*)(&rows[j][8]);
      const float4* Cv = (const float4*)(&rows[j][24]);
      float y = 0.f;
      #pragma unroll
      for (int q=0;q<4;q++) {
        float4 bv = Bv[q];
        float4 cv = Cv[q];
        h[4*q+0] = h[4*q+0]*__builtin_amdgcn_exp2f(dt*A2[4*q+0]) + du*bv.x;
        h[4*q+1] = h[4*q+1]*__builtin_amdgcn_exp2f(dt*A2[4*q+1]) + du*bv.y;
        h[4*q+2] = h[4*q+2]*__builtin_amdgcn_exp2f(dt*A2[4*q+2]) + du*bv.z;
        h[4*q+3] = h[4*q+3]*__builtin_amdgcn_exp2f(dt*A2[4*q+3]) + du*bv.w;
        y += h[4*q+0]*cv.x + h[4*q+1]*cv.y + h[4*q+2]*cv.z + h[4*q+3]*cv.w;
      }
      int p = pbase + j*pstr;
      ymk[(size_t)p*DI + c] = y;
    }
  }
}

// fused: merge 4 dirs + D + chanLN(192) + out_proj + skip -> out
__global__ __launch_bounds__(384) void k_merge_out(const float* __restrict__ ym,
    const float* __restrict__ v_t, const float* __restrict__ Ds,
    const float* __restrict__ g, const float* __restrict__ be,
    const float* __restrict__ w3, const float* __restrict__ x1,
    const float* __restrict__ ss, float* __restrict__ out) {
  __shared__ float tile2[16*196];
  __shared__ float red[2][16][6];
  int t = threadIdx.x;
  int b = blockIdx.y;
  int l0 = blockIdx.x*16;
  int pp = t / 192, c = t - pp*192;
  int wv = t >> 6;
  int ln = t & 63;
  float sd = Ds[c] + Ds[DI+c] + Ds[2*DI+c] + Ds[3*DI+c];
  float gg = g[c], bb = be[c];
  float v[8];
  #pragma unroll
  for (int j=0;j<8;j++) {
    int i = 2*j + pp;
    size_t row = ((size_t)b*LL + l0 + i)*DI + c;
    float vv = ym[row] + ym[(size_t)2*LL*DI + row]
             + ym[(size_t)4*LL*DI + row] + ym[(size_t)6*LL*DI + row]
             + v_t[row]*sd;
    v[j] = vv;
    float s = vv, s2 = vv*vv;
    #pragma unroll
    for (int d=1; d<64; d<<=1) { s += __shfl_xor(s,d); s2 += __shfl_xor(s2,d); }
    if (ln==0) { red[0][i][wv]=s; red[1][i][wv]=s2; }
  }
  __syncthreads();
  #pragma unroll
  for (int j=0;j<8;j++) {
    int i = 2*j + pp;
    int w0i = pp*3;
    float S  = red[0][i][w0i]+red[0][i][w0i+1]+red[0][i][w0i+2];
    float S2 = red[1][i][w0i]+red[1][i][w0i+1]+red[1][i][w0i+2];
    float mu = S*(1.f/DI);
    float var = S2*(1.f/DI) - mu*mu;
    float r = rsqrtf(var + LNEPS);
    tile2[i*196 + c] = (v[j]-mu)*r*gg + bb;
  }
  __syncthreads();
  int l = t & 15, og = t >> 4;
  float a0=0.f,a1=0.f,a2=0.f,a3=0.f;
  {
    const float4* yr = (const float4*)&tile2[l*196];
    const float4* wr0 = (const float4*)(w3 + (size_t)(og*4+0)*DI);
    const float4* wr1 = (const float4*)(w3 + (size_t)(og*4+1)*DI);
    const float4* wr2 = (const float4*)(w3 + (size_t)(og*4+2)*DI);
    const float4* wr3 = (const float4*)(w3 + (size_t)(og*4+3)*DI);
    #pragma unroll 6
    for (int j=0;j<48;j++) {
      float4 yv = yr[j];
      float4 v0 = wr0[j], v1 = wr1[j], v2 = wr2[j], v3 = wr3[j];
      a0 += yv.x*v0.x + yv.y*v0.y + yv.z*v0.z + yv.w*v0.w;
      a1 += yv.x*v1.x + yv.y*v1.y + yv.z*v1.z + yv.w*v1.w;
      a2 += yv.x*v2.x + yv.y*v2.y + yv.z*v2.z + yv.w*v2.w;
      a3 += yv.x*v3.x + yv.y*v3.y + yv.z*v3.z + yv.w*v3.w;
    }
  }
  float sc = ss[0];
  int o0 = og*4;
  size_t ob = ((size_t)b*HD + o0)*LL + l0 + l;
  out[ob]            = a0 + x1[ob]*sc;
  out[ob+LL]         = a1 + x1[ob+LL]*sc;
  out[ob+2*(size_t)LL] = a2 + x1[ob+2*(size_t)LL]*sc;
  out[ob+3*(size_t)LL] = a3 + x1[ob+3*(size_t)LL]*sc;
}

extern "C" void kernel_launch(void* const* d_in, const int* in_sizes, int n_in,
                              void* d_out, int out_size, void* d_ws, size_t ws_size,
                              hipStream_t stream) {
  const float* x         = (const float*)d_in[0];
  const float* in_conv_w = (const float*)d_in[1];
  const float* ln1_g     = (const float*)d_in[2];
  const float* ln1_b     = (const float*)d_in[3];
  const float* in_proj_w = (const float*)d_in[4];
  const float* dw_w      = (const float*)d_in[5];
  const float* dw_b      = (const float*)d_in[6];
  const float* x_proj_w  = (const float*)d_in[7];
  const float* dt_proj_w = (const float*)d_in[8];
  const float* dt_proj_b = (const float*)d_in[9];
  const float* A_log     = (const float*)d_in[10];
  const float* Ds        = (const float*)d_in[11];
  const float* onorm_g   = (const float*)d_in[12];
  const float* onorm_b   = (const float*)d_in[13];
  const float* out_proj_w= (const float*)d_in[14];
  const float* skip_s    = (const float*)d_in[15];
  float* out = (float*)d_out;

  float* ws   = (float*)d_ws;
  float* x1   = ws;                  //   786,432
  float* hp   = x1   + 786432;       // 1,572,864
  float* v_t  = hp   + 1572864;      // 1,572,864
  float* dblp = v_t  + 1572864;      // 1,310,720
  float* hend = dblp + 1310720;      // 6,291,456
  float* sdt  = hend + 6291456;      //   393,216
  float* ym   = sdt  + 393216;       // 6,291,456 (4 x [b][p][c])

  k_fused_in<<<dim3(LL/16, Bb), dim3(384), 0, stream>>>(x, in_conv_w, ln1_g, ln1_b, in_proj_w, x1, hp);
  k_dwconv_silu_t<<<dim3(64, 8, Bb), dim3(192), 0, stream>>>(hp, dw_w, dw_b, v_t);
  k_proj   <<<dim3(LL/64, Kd, Bb), dim3(512), 0, stream>>>(v_t, x_proj_w, dblp);
  {
    void* args[8];
    args[0] = (void*)&v_t;
    args[1] = (void*)&dblp;
    args[2] = (void*)&dt_proj_w;
    args[3] = (void*)&dt_proj_b;
    args[4] = (void*)&A_log;
    args[5] = (void*)&hend;
    args[6] = (void*)&sdt;
    args[7] = (void*)&ym;
    hipLaunchCooperativeKernel((void*)k_scan_all, dim3(512), dim3(192), args, 0, stream);
  }
  k_merge_out<<<dim3(LL/16, Bb), dim3(384), 0, stream>>>(ym, v_t, Ds, onorm_g, onorm_b, out_proj_w, x1, skip_s, out);
}